// Round 2
// baseline (122.742 us; speedup 1.0000x reference)
//
#include <hip/hip_runtime.h>

// ChannelKiller: out[b,c,s] = (c==0) ? x[b,c,s] : 0
// x: [16, 8, 1048576] fp32.
// Phase-split: pure-store zero-fill (channels 1..7, 448 MiB) at fill-kernel BW,
// then dense copy of channel 0 (64 MiB read + 64 MiB write).

typedef float f32x4 __attribute__((ext_vector_type(4)));

#define S_LOG2 18          // float4 per channel row = 1048576/4 = 2^18
#define NCH 8

// Pure-write zero kernel: grid-stride over the whole output, stores only where
// channel != 0. The skip is wave-uniform (channel segments are 2^18 float4),
// so channel-0 iterations cost only loop arithmetic, no memory ops.
__global__ void ChannelKiller_zero_kernel(f32x4* __restrict__ out, int n4) {
    int i = blockIdx.x * blockDim.x + threadIdx.x;
    const int stride = gridDim.x * blockDim.x;
    const f32x4 z = {0.f, 0.f, 0.f, 0.f};
    for (; i < n4; i += stride) {
        int c = (i >> S_LOG2) & (NCH - 1);
        if (c != 0) {
            // non-temporal: don't let 448 MiB of zeros thrash L3 (keep x ch0 resident)
            __builtin_nontemporal_store(z, &out[i]);
        }
    }
}

// Dense copy kernel over channel-0 float4s only: m4 = 16 * 2^18 indices,
// mapped to flat address (batch << (S_LOG2+3)) | within-row offset.
__global__ void ChannelKiller_copy_kernel(const f32x4* __restrict__ x,
                                          f32x4* __restrict__ out, int m4) {
    int i = blockIdx.x * blockDim.x + threadIdx.x;
    const int stride = gridDim.x * blockDim.x;
    for (; i < m4; i += stride) {
        int addr = ((i >> S_LOG2) << (S_LOG2 + 3)) | (i & ((1 << S_LOG2) - 1));
        out[addr] = x[addr];
    }
}

extern "C" void kernel_launch(void* const* d_in, const int* in_sizes, int n_in,
                              void* d_out, int out_size, void* d_ws, size_t ws_size,
                              hipStream_t stream) {
    const f32x4* x = (const f32x4*)d_in[0];
    f32x4* out = (f32x4*)d_out;
    int n4 = out_size / 4;              // 33554432 float4 total
    int m4 = n4 / NCH;                  // 4194304 float4 in channel 0 (all batches)

    const int block = 256;
    const int grid = 2048;              // 8 blocks/CU resident, grid-stride covers rest

    ChannelKiller_zero_kernel<<<grid, block, 0, stream>>>(out, n4);
    ChannelKiller_copy_kernel<<<grid, block, 0, stream>>>(x, out, m4);
}